// Round 3
// baseline (195.622 us; speedup 1.0000x reference)
//
#include <hip/hip_runtime.h>
#include <cstdint>
#include <cstddef>

#define HID 1024
#define NH 16
#define HD 64
#define BB 2
#define LL 2048
#define MM (BB*LL)       // 4096 rows
#define CHUNK 64
#define NT (LL/CHUNK)    // 32 chunks
#define BHn (BB*NH)      // 32 (b,h) chains

typedef __bf16 bf16;
typedef __attribute__((ext_vector_type(8))) __bf16 bf16x8;
typedef __attribute__((ext_vector_type(4))) float f32x4;

__device__ __forceinline__ f32x4 mfma16(bf16x8 a, bf16x8 b, f32x4 c){
  return __builtin_amdgcn_mfma_f32_16x16x32_bf16(a, b, c, 0, 0, 0);
}

__device__ __forceinline__ void gload16(const void* g, void* l){
  __builtin_amdgcn_global_load_lds(
      (const __attribute__((address_space(1))) unsigned int*)g,
      (__attribute__((address_space(3))) unsigned int*)l, 16, 0, 0);
}

__device__ __forceinline__ void barx(){
  asm volatile("" ::: "memory");
  __builtin_amdgcn_s_barrier();
  asm volatile("" ::: "memory");
}

// ---------------- cast fp32 -> bf16 ----------------
__global__ void cast_x_k(const float* __restrict__ src, bf16* __restrict__ dst){
  int i = blockIdx.x*256 + threadIdx.x;
  float4 v = ((const float4*)src)[i];
  union { bf16 h[4]; uint2 u; } pk;
  pk.h[0]=(bf16)v.x; pk.h[1]=(bf16)v.y; pk.h[2]=(bf16)v.z; pk.h[3]=(bf16)v.w;
  *((uint2*)(dst + 4*(size_t)i)) = pk.u;
}

__global__ void cast_w_k(const float* __restrict__ w0,const float* __restrict__ w1,
                         const float* __restrict__ w2,const float* __restrict__ w3,
                         bf16* __restrict__ d0, bf16* __restrict__ d1,
                         bf16* __restrict__ d2, bf16* __restrict__ d3){
  const float* s; bf16* d;
  switch(blockIdx.y){ case 0: s=w0; d=d0; break; case 1: s=w1; d=d1; break;
                      case 2: s=w2; d=d2; break; default: s=w3; d=d3; }
  int i = blockIdx.x*256 + threadIdx.x;
  float4 v = ((const float4*)s)[i];
  union { bf16 h[4]; uint2 u; } pk;
  pk.h[0]=(bf16)v.x; pk.h[1]=(bf16)v.y; pk.h[2]=(bf16)v.z; pk.h[3]=(bf16)v.w;
  *((uint2*)(d + 4*(size_t)i)) = pk.u;
}

// ---------------- 256x256 8-wave counted-vmcnt GEMM ----------------
// C[m,n] = sum_k A[m,k]*W[n,k].  BK=32, K-tiles NKT=32.
// LDS: 3 tile-buffers x 4 pieces [128 rows][32 cols] bf16 = 96 KiB.
// pieces: 0=A rows[0,128), 1=A rows[128,256), 2=B rows[0,128), 3=B rows[128,256)
// XOR swizzle: physical chunk = logical chunk ^ ((row>>1)&3); applied on the
// GLOBAL source col (gload_lds dest must stay linear) and on ds_read addr.
// Schedule: phase(t,h): stage 2 pieces of tile t+2; ds_read frags; vmcnt(4)@h==1;
// barrier; setprio(1); 16 MFMA; setprio(0); barrier.  vmcnt->0 only at tail.
// MODE 0: QKV fused (N=3072, grid 12x16), elu+1 on Q,K; writes Q/Kn/Vn (M,HID).
//         bn is masked to bn&3 for BOTH weight rows and output column (bug fix).
// MODE 1: out-proj (N=1024, grid 4x16), fp32 store.
template<int MODE>
__global__ __launch_bounds__(512) void gemm8_k(
    const bf16* __restrict__ A,
    const bf16* __restrict__ W0, const bf16* __restrict__ W1, const bf16* __restrict__ W2,
    bf16* __restrict__ Qo, bf16* __restrict__ Kn, bf16* __restrict__ Vn,
    float* __restrict__ Outf)
{
  constexpr int NKT = HID/32;
  __shared__ bf16 lds[3][4][128*32];
  const int tid = threadIdx.x;
  const int wv = tid >> 6, lane = tid & 63;
  const int lrow = lane & 15, g4 = lane >> 4;
  const int wr = wv >> 2, wc = wv & 3;
  const int bm = blockIdx.y;
  const int bn = blockIdx.x;
  int wsel = 0, bnl = bn;
  const bf16* W = W0;
  if (MODE==0){ wsel = bn >> 2; bnl = bn & 3; W = (wsel==0)?W0:((wsel==1)?W1:W2); }
  const int row0 = bm*256, col0 = bnl*256;   // col0 valid for W rows AND output cols

  // staging addressing: thread -> (row sr 0..127, chunk sc 0..3) of a piece
  const int sr = tid >> 2, sc = tid & 3;
  const int scs = sc ^ ((sr>>1)&3);                  // swizzled source chunk
  const bf16* gA0 = A + ((size_t)(row0 + sr))*HID + scs*8;
  const bf16* gA1 = gA0 + (size_t)128*HID;
  const bf16* gB0 = W + ((size_t)(col0 + sr))*HID + scs*8;
  const bf16* gB1 = gB0 + (size_t)128*HID;
  const int ldsbase = wv*512;                        // wave-uniform piece offset

  auto stage = [&](int P){
    if (P >= 4*NKT) return;
    int u = P >> 2, q = P & 3, buf = u % 3;
    const bf16* g = (q==0)?gA0:((q==1)?gA1:((q==2)?gB0:gB1));
    gload16(g + u*32, (void*)&lds[buf][q][ldsbase]);
  };

  const int koff = (g4 ^ ((lrow>>1)&3)) << 3;        // swizzled chunk on read
  const int bpiece = 2 + (wc>>1);
  const int brow0 = (wc&1)*64;

  f32x4 acc[8][4] = {};
  bf16x8 bfrag[4];

  #pragma unroll
  for (int P=0; P<8; ++P) stage(P);                  // tiles 0,1
  asm volatile("s_waitcnt vmcnt(4)" ::: "memory");   // tile 0 landed
  barx();

  for (int t=0; t<NKT; ++t){
    const int buf = t % 3;
    // ---- phase h=0: frag-rows 0..3, load all B frags ----
    {
      stage(8+4*t); stage(9+4*t);                    // tile t+2 pieces 0,1
      bf16x8 afr[4];
      #pragma unroll
      for (int i=0;i<4;i++)
        afr[i] = *(const bf16x8*)&lds[buf][wr][((i*16+lrow)<<5) + koff];
      #pragma unroll
      for (int j=0;j<4;j++)
        bfrag[j] = *(const bf16x8*)&lds[buf][bpiece][((brow0 + j*16 + lrow)<<5) + koff];
      barx();
      __builtin_amdgcn_s_setprio(1);
      #pragma unroll
      for (int i=0;i<4;i++)
        #pragma unroll
        for (int j=0;j<4;j++)
          acc[i][j] = mfma16(afr[i], bfrag[j], acc[i][j]);
      __builtin_amdgcn_s_setprio(0);
      barx();
    }
    // ---- phase h=1: frag-rows 4..7 ----
    {
      stage(10+4*t); stage(11+4*t);                  // tile t+2 pieces 2,3
      bf16x8 afr[4];
      #pragma unroll
      for (int i=0;i<4;i++)
        afr[i] = *(const bf16x8*)&lds[buf][wr][(((i+4)*16+lrow)<<5) + koff];
      if (t < NKT-2) { asm volatile("s_waitcnt vmcnt(4)" ::: "memory"); }
      else           { asm volatile("s_waitcnt vmcnt(0)" ::: "memory"); }
      barx();
      __builtin_amdgcn_s_setprio(1);
      #pragma unroll
      for (int i=0;i<4;i++)
        #pragma unroll
        for (int j=0;j<4;j++)
          acc[i+4][j] = mfma16(afr[i], bfrag[j], acc[i+4][j]);
      __builtin_amdgcn_s_setprio(0);
      barx();
    }
  }

  // ---- epilogue ----
  #pragma unroll
  for (int i=0;i<8;i++){
    const int m0 = row0 + wr*128 + i*16 + g4*4;
    #pragma unroll
    for (int j=0;j<4;j++){
      const int c = col0 + wc*64 + j*16 + lrow;
      #pragma unroll
      for (int r=0;r<4;r++){
        float v = acc[i][j][r];
        if (MODE==1){
          Outf[(size_t)(m0+r)*HID + c] = v;
        } else {
          if (wsel<2) v = v>0.f ? v+1.f : __expf(v);   // elu(v)+1
          bf16 bv = (bf16)v;
          if      (wsel==0) Qo[(size_t)(m0+r)*HID + c] = bv;
          else if (wsel==1) Kn[(size_t)(m0+r)*HID + c] = bv;
          else              Vn[(size_t)(m0+r)*HID + c] = bv;
        }
      }
    }
  }
}

// ---------------- transpose (M,HID)->(BH,D,L), coalesced both sides ----------------
__global__ __launch_bounds__(256) void trans_k(const bf16* __restrict__ Kn, const bf16* __restrict__ Vn,
                                               bf16* __restrict__ Kt, bf16* __restrict__ Vt){
  __shared__ bf16 T[64][72];
  const bf16* src = blockIdx.z ? Vn : Kn;
  bf16* dst = blockIdx.z ? Vt : Kt;
  const int bh = blockIdx.y;
  const int b = bh >> 4, h = bh & 15;
  const int l0 = blockIdx.x * 64;
  const int t = threadIdx.x;
  const int lr = t >> 2, c4 = t & 3;
  const bf16* s = src + ((size_t)(b*LL + l0 + lr))*HID + h*HD;
  *(bf16x8*)&T[lr][c4*8]      = *(const bf16x8*)&s[c4*8];
  *(bf16x8*)&T[lr][c4*8 + 32] = *(const bf16x8*)&s[c4*8 + 32];
  __syncthreads();
  bf16* dd = dst + ((size_t)bh*HD + lr)*LL + l0;
  bf16x8 o0, o1;
  #pragma unroll
  for (int e=0;e<8;e++){ o0[e] = T[c4*8+e][lr]; o1[e] = T[c4*8+32+e][lr]; }
  *(bf16x8*)&dd[c4*8] = o0;
  *(bf16x8*)&dd[c4*8+32] = o1;
}

// ---------------- pass1: per-chunk SkvT[e][d] = sum_j v_j[e] k_j[d], ksum[d] ----------------
__global__ __launch_bounds__(64) void pass1_k(const bf16* __restrict__ Kt, const bf16* __restrict__ Vt,
                                              float* __restrict__ SkvT, float* __restrict__ ksum)
{
  const int blk = blockIdx.x;                 // bh*NT + t
  const int bh = blk >> 5, t = blk & (NT-1);
  const int lane = threadIdx.x;
  const int lrow = lane&15, g4 = lane>>4, lk8 = g4*8;
  const bf16* vtb = Vt + (size_t)bh*HD*LL + t*CHUNK;
  const bf16* ktb = Kt + (size_t)bh*HD*LL + t*CHUNK;
  bf16x8 av[4][2], bk[4][2];
  #pragma unroll
  for (int i=0;i<4;i++)
    #pragma unroll
    for (int kk=0;kk<2;kk++){
      av[i][kk] = *(const bf16x8*)&vtb[(size_t)(i*16+lrow)*LL + kk*32 + lk8];
      bk[i][kk] = *(const bf16x8*)&ktb[(size_t)(i*16+lrow)*LL + kk*32 + lk8];
    }
  f32x4 acc[4][4] = {};
  #pragma unroll
  for (int i=0;i<4;i++)
    #pragma unroll
    for (int j=0;j<4;j++)
      #pragma unroll
      for (int kk=0;kk<2;kk++)
        acc[i][j] = mfma16(av[i][kk], bk[j][kk], acc[i][j]);
  float* so = SkvT + (size_t)blk*4096;
  #pragma unroll
  for (int i=0;i<4;i++)
    #pragma unroll
    for (int j=0;j<4;j++)
      #pragma unroll
      for (int r=0;r<4;r++)
        so[(i*16+g4*4+r)*64 + j*16+lrow] = acc[i][j][r];
  const bf16* krow = ktb + (size_t)lane*LL;
  float s = 0.f;
  #pragma unroll
  for (int c8=0;c8<8;c8++){
    bf16x8 v = *(const bf16x8*)&krow[c8*8];
    #pragma unroll
    for (int j=0;j<8;j++) s += (float)v[j];
  }
  ksum[(size_t)blk*64 + lane] = s;
}

// ---------------- pass2: exclusive prefix scan over chunks ----------------
__global__ __launch_bounds__(256) void pass2_k(const float* __restrict__ SkvT, const float* __restrict__ ksum,
                                               bf16* __restrict__ Sexcl, float* __restrict__ ksx)
{
  int gid = blockIdx.x*256 + threadIdx.x;
  if (gid < BHn*4096){
    int bh = gid >> 12, e = gid & 4095;
    float run = 0.f;
    size_t base = (size_t)bh*NT*4096 + e;
    for (int t=0;t<NT;t++){
      Sexcl[base + (size_t)t*4096] = (bf16)run;
      run += SkvT[base + (size_t)t*4096];
    }
  } else if (gid < BHn*4096 + BHn*64){
    int g2 = gid - BHn*4096;
    int bh = g2 >> 6, d = g2 & 63;
    float run = 0.f;
    size_t base = (size_t)bh*NT*64 + d;
    for (int t=0;t<NT;t++){
      ksx[base + (size_t)t*64] = run;
      run += ksum[base + (size_t)t*64];
    }
  }
}

// ---------------- pass3: per (b,h,chunk) output ----------------
__global__ __launch_bounds__(64) void pass3_k(const bf16* __restrict__ Q, const bf16* __restrict__ Kn,
                                              const bf16* __restrict__ Sexcl, const bf16* __restrict__ Vt,
                                              const float* __restrict__ ksx, bf16* __restrict__ Obuf)
{
  __shared__ bf16 P[64*72];
  const int blk = blockIdx.x;
  const int bh = blk>>5, t = blk&(NT-1);
  const int b = bh>>4, h = bh&15;
  const int lane = threadIdx.x;
  const int lrow = lane&15, g4 = lane>>4, lk8 = g4*8;
  const bf16* qb = Q  + ((size_t)(b*LL + t*CHUNK))*HID + h*HD;
  const bf16* kb = Kn + ((size_t)(b*LL + t*CHUNK))*HID + h*HD;
  bf16x8 aq[4][2], bk[4][2];
  #pragma unroll
  for (int i=0;i<4;i++)
    #pragma unroll
    for (int kk=0;kk<2;kk++){
      aq[i][kk] = *(const bf16x8*)&qb[(size_t)(i*16+lrow)*HID + kk*32 + lk8];
      bk[i][kk] = *(const bf16x8*)&kb[(size_t)(i*16+lrow)*HID + kk*32 + lk8];
    }
  f32x4 sacc[4][4] = {};
  #pragma unroll
  for (int i=0;i<4;i++)
    #pragma unroll
    for (int j=0;j<4;j++)
      #pragma unroll
      for (int kk=0;kk<2;kk++)
        sacc[i][j] = mfma16(aq[i][kk], bk[j][kk], sacc[i][j]);
  float rs[4][4];
  #pragma unroll
  for (int i=0;i<4;i++)
    #pragma unroll
    for (int r=0;r<4;r++){
      int irow = i*16 + g4*4 + r;
      float p = 0.f;
      #pragma unroll
      for (int j=0;j<4;j++){
        int jcol = j*16 + lrow;
        float v = (jcol <= irow) ? sacc[i][j][r] : 0.f;
        sacc[i][j][r] = v;
        p += v;
      }
      p += __shfl_xor(p,1); p += __shfl_xor(p,2);
      p += __shfl_xor(p,4); p += __shfl_xor(p,8);
      rs[i][r] = p;
    }
  #pragma unroll
  for (int i=0;i<4;i++)
    #pragma unroll
    for (int j=0;j<4;j++)
      #pragma unroll
      for (int r=0;r<4;r++)
        P[(i*16+g4*4+r)*72 + j*16+lrow] = (bf16)sacc[i][j][r];
  const float* kp = ksx + (size_t)blk*64;
  float zA[4];
  #pragma unroll
  for (int i=0;i<4;i++){
    float s = 0.f;
    #pragma unroll
    for (int kk=0;kk<2;kk++){
      const float* k8 = kp + kk*32 + lk8;
      bf16x8 q = aq[i][kk];
      #pragma unroll
      for (int j=0;j<8;j++) s += (float)q[j] * k8[j];
    }
    s += __shfl_xor(s,16); s += __shfl_xor(s,32);
    zA[i] = s;
  }
  const bf16* sb = Sexcl + (size_t)blk*4096;
  f32x4 oacc[4][4] = {};
  bf16x8 bs[4][2];
  #pragma unroll
  for (int j=0;j<4;j++)
    #pragma unroll
    for (int kk=0;kk<2;kk++)
      bs[j][kk] = *(const bf16x8*)&sb[(size_t)(j*16+lrow)*64 + kk*32 + lk8];
  #pragma unroll
  for (int i=0;i<4;i++)
    #pragma unroll
    for (int j=0;j<4;j++)
      #pragma unroll
      for (int kk=0;kk<2;kk++)
        oacc[i][j] = mfma16(aq[i][kk], bs[j][kk], oacc[i][j]);
  __syncthreads();
  const bf16* vb = Vt + (size_t)bh*HD*LL + t*CHUNK;
  bf16x8 bv[4][2], ap[4][2];
  #pragma unroll
  for (int j=0;j<4;j++)
    #pragma unroll
    for (int kk=0;kk<2;kk++)
      bv[j][kk] = *(const bf16x8*)&vb[(size_t)(j*16+lrow)*LL + kk*32 + lk8];
  #pragma unroll
  for (int i=0;i<4;i++)
    #pragma unroll
    for (int kk=0;kk<2;kk++)
      ap[i][kk] = *(const bf16x8*)&P[(i*16+lrow)*72 + kk*32 + lk8];
  #pragma unroll
  for (int i=0;i<4;i++)
    #pragma unroll
    for (int j=0;j<4;j++)
      #pragma unroll
      for (int kk=0;kk<2;kk++)
        oacc[i][j] = mfma16(ap[i][kk], bv[j][kk], oacc[i][j]);
  bf16* ob = Obuf + ((size_t)(b*LL + t*CHUNK))*HID + h*HD;
  #pragma unroll
  for (int i=0;i<4;i++)
    #pragma unroll
    for (int r=0;r<4;r++){
      float z = __shfl(zA[i], g4*4 + r) + rs[i][r];
      z = fmaxf(z, 1e-6f);
      float inv = 1.0f/z;
      int irow = i*16 + g4*4 + r;
      #pragma unroll
      for (int j=0;j<4;j++)
        ob[(size_t)irow*HID + j*16+lrow] = (bf16)(oacc[i][j][r]*inv);
    }
}

// ---------------- launch ----------------
extern "C" void kernel_launch(void* const* d_in, const int* in_sizes, int n_in,
                              void* d_out, int out_size, void* d_ws, size_t ws_size,
                              hipStream_t stream)
{
  const float* x  = (const float*)d_in[0];
  const float* Wq = (const float*)d_in[1];
  const float* Wk = (const float*)d_in[2];
  const float* Wv = (const float*)d_in[3];
  const float* Wo = (const float*)d_in[4];
  float* out = (float*)d_out;

  char* p = (char*)d_ws;
  auto alloc = [&](size_t bytes){ void* r = (void*)p; p += (bytes + 255) & ~(size_t)255; return r; };
  bf16* xb   = (bf16*)alloc((size_t)MM*HID*2);
  bf16* Wqb  = (bf16*)alloc((size_t)HID*HID*2);
  bf16* Wkb  = (bf16*)alloc((size_t)HID*HID*2);
  bf16* Wvb  = (bf16*)alloc((size_t)HID*HID*2);
  bf16* Wob  = (bf16*)alloc((size_t)HID*HID*2);
  bf16* Qb   = (bf16*)alloc((size_t)MM*HID*2);
  bf16* Knb  = (bf16*)alloc((size_t)MM*HID*2);
  bf16* Vnb  = (bf16*)alloc((size_t)MM*HID*2);
  bf16* Ktb  = (bf16*)alloc((size_t)MM*HID*2);        // (BH, D, L)
  bf16* Vtb  = (bf16*)alloc((size_t)MM*HID*2);        // (BH, D, L)
  bf16* Ob   = (bf16*)alloc((size_t)MM*HID*2);
  float* SkvT  = (float*)alloc((size_t)BHn*NT*4096*4);
  bf16*  Sexcl = (bf16*) alloc((size_t)BHn*NT*4096*2);
  float* ksum  = (float*)alloc((size_t)BHn*NT*64*4);
  float* ksx   = (float*)alloc((size_t)BHn*NT*64*4);

  cast_x_k<<<dim3(MM*HID/4/256), 256, 0, stream>>>(x, xb);
  cast_w_k<<<dim3(HID*HID/4/256, 4), 256, 0, stream>>>(Wq,Wk,Wv,Wo, Wqb,Wkb,Wvb,Wob);
  gemm8_k<0><<<dim3(12,16), 512, 0, stream>>>(xb, Wqb,Wkb,Wvb, Qb,Knb,Vnb, nullptr);
  trans_k<<<dim3(LL/64, BHn, 2), 256, 0, stream>>>(Knb, Vnb, Ktb, Vtb);
  pass1_k<<<dim3(BHn*NT), 64, 0, stream>>>(Ktb, Vtb, SkvT, ksum);
  pass2_k<<<dim3((BHn*4096 + BHn*64 + 255)/256), 256, 0, stream>>>(SkvT, ksum, Sexcl, ksx);
  pass3_k<<<dim3(BHn*NT), 64, 0, stream>>>(Qb, Knb, Sexcl, Vtb, ksx, Ob);
  gemm8_k<1><<<dim3(4,16), 512, 0, stream>>>(Ob, Wob,nullptr,nullptr, nullptr,nullptr,nullptr, out);
}

// Round 4
// 171.888 us; speedup vs baseline: 1.1381x; 1.1381x over previous
//
#include <hip/hip_runtime.h>
#include <cstdint>
#include <cstddef>

#define HID 1024
#define NH 16
#define HD 64
#define BB 2
#define LL 2048
#define MM (BB*LL)       // 4096 rows
#define CHUNK 64
#define NT (LL/CHUNK)    // 32 chunks
#define BHn (BB*NH)      // 32 (b,h) chains

typedef __bf16 bf16;
typedef __attribute__((ext_vector_type(8))) __bf16 bf16x8;
typedef __attribute__((ext_vector_type(4))) float f32x4;

__device__ __forceinline__ f32x4 mfma16(bf16x8 a, bf16x8 b, f32x4 c){
  return __builtin_amdgcn_mfma_f32_16x16x32_bf16(a, b, c, 0, 0, 0);
}

__device__ __forceinline__ void gload16(const void* g, void* l){
  __builtin_amdgcn_global_load_lds(
      (const __attribute__((address_space(1))) unsigned int*)g,
      (__attribute__((address_space(3))) unsigned int*)l, 16, 0, 0);
}

__device__ __forceinline__ void barx(){
  asm volatile("" ::: "memory");
  __builtin_amdgcn_s_barrier();
  asm volatile("" ::: "memory");
}

#define WAITVM(N) asm volatile("s_waitcnt vmcnt(" #N ")" ::: "memory")

// ---------------- fused cast fp32 -> bf16 (x + 4 weights, one launch) ----------------
__global__ __launch_bounds__(256) void cast_all_k(
    const float* __restrict__ x,  const float* __restrict__ w0,
    const float* __restrict__ w1, const float* __restrict__ w2, const float* __restrict__ w3,
    bf16* __restrict__ xb, bf16* __restrict__ d0, bf16* __restrict__ d1,
    bf16* __restrict__ d2, bf16* __restrict__ d3)
{
  int bid = blockIdx.x;                   // 0..8191
  const float* s; bf16* d; int base;
  if (bid < 4096){ s = x; d = xb; base = bid; }
  else {
    int w = (bid - 4096) >> 10, r = (bid - 4096) & 1023;
    s = (w==0)?w0:(w==1)?w1:(w==2)?w2:w3;
    d = (w==0)?d0:(w==1)?d1:(w==2)?d2:d3;
    base = r;
  }
  int i = base*256 + threadIdx.x;
  float4 v = ((const float4*)s)[i];
  union { bf16 h[4]; uint2 u; } pk;
  pk.h[0]=(bf16)v.x; pk.h[1]=(bf16)v.y; pk.h[2]=(bf16)v.z; pk.h[3]=(bf16)v.w;
  *((uint2*)(d + 4*(size_t)i)) = pk.u;
}

// ---------------- software-pipelined 8-wave GEMM ----------------
// C[m,n] = sum_k A[m,k]*W[n,k].  BK=32, NKT=32 K-tiles.
// MODE 0: QKV fused. BM=BN=256, grid (12,16). elu+1 on Q,K. LDS 128 KiB.
// MODE 1: out-proj.  BM=BN=128, grid (8,32). fp32 store.  LDS 64 KiB.
// Pipeline per iter t: stage tile t+3 (4 LDS bufs, 3 ahead); vmcnt(2*PPT)
// [tile t+1 landed]; barrier; ds_read frags(t+1) into the spare reg set;
// MFMA(t) on the current set (operands read last iter -> LDS pipe and MFMA
// pipe overlap within the iter). vmcnt never drains to 0 until the tail.
// XOR swizzle chunk^((row>>1)&3): applied on global source (gload_lds dest
// must stay linear) and on ds_read addr; 2-way max bank aliasing (free).
template<int MODE>
__global__ __launch_bounds__(512, 2) void gemm8_k(
    const bf16* __restrict__ A,
    const bf16* __restrict__ W0, const bf16* __restrict__ W1, const bf16* __restrict__ W2,
    bf16* __restrict__ Qo, bf16* __restrict__ Kn, bf16* __restrict__ Vn,
    float* __restrict__ Outf)
{
  constexpr int BM  = (MODE==0) ? 256 : 128;
  constexpr int BN  = (MODE==0) ? 256 : 128;
  constexpr int AP  = BM/128;           // A pieces per tile
  constexpr int BP  = BN/128;           // B pieces per tile
  constexpr int PPT = AP + BP;          // pieces per tile (4 or 2)
  constexpr int NA  = BM/32;            // A frags per wave (8 or 4)
  constexpr int NBF = BN/64;            // B frags per wave (4 or 2)
  constexpr int NKT = HID/32;
  __shared__ bf16 lds[4][PPT][128*32];

  const int tid = threadIdx.x;
  const int wv = tid >> 6, lane = tid & 63;
  const int lrow = lane & 15, g4 = lane >> 4;
  const int wr = wv >> 2, wc = wv & 3;
  int bn = blockIdx.x, wsel = 0;
  const bf16* W = W0;
  if (MODE==0){ wsel = bn >> 2; bn &= 3; W = (wsel==0)?W0:((wsel==1)?W1:W2); }
  const int row0 = blockIdx.y*BM, col0 = bn*BN;

  // staging: thread -> (row sr, chunk sc) of each 128x32 piece
  const int sr = tid >> 2, sc = tid & 3;
  const int scs = sc ^ ((sr>>1)&3);              // pre-swizzled source chunk
  const bf16* gA0 = A + (size_t)(row0 + sr)*HID + scs*8;
  const bf16* gA1 = gA0 + (size_t)128*HID;       // used only if AP==2
  const bf16* gB0 = W + (size_t)(col0 + sr)*HID + scs*8;
  const bf16* gB1 = gB0 + (size_t)128*HID;       // used only if BP==2
  const int ldst = tid*8;                        // element offset in piece

  auto stage_tile = [&](int u){
    const int buf = u & 3;
    gload16(gA0 + u*32, (void*)&lds[buf][0][ldst]);
    if constexpr (AP==2) gload16(gA1 + u*32, (void*)&lds[buf][1][ldst]);
    gload16(gB0 + u*32, (void*)&lds[buf][AP][ldst]);
    if constexpr (BP==2) gload16(gB1 + u*32, (void*)&lds[buf][AP+1][ldst]);
  };

  const int koff = (g4 ^ ((lrow>>1)&3)) << 3;    // swizzled chunk on read

  auto read_frags = [&](int u, bf16x8 (&fa)[NA], bf16x8 (&fb)[NBF]){
    const int buf = u & 3;
    #pragma unroll
    for (int i=0;i<NA;i++){
      if constexpr (MODE==0)
        fa[i] = *(const bf16x8*)&lds[buf][wr][((i*16+lrow)<<5) + koff];
      else
        fa[i] = *(const bf16x8*)&lds[buf][0][((wr*64 + i*16+lrow)<<5) + koff];
    }
    #pragma unroll
    for (int j=0;j<NBF;j++){
      if constexpr (MODE==0)
        fb[j] = *(const bf16x8*)&lds[buf][2+(wc>>1)][(((wc&1)*64 + j*16+lrow)<<5) + koff];
      else
        fb[j] = *(const bf16x8*)&lds[buf][1][((wc*32 + j*16+lrow)<<5) + koff];
    }
  };

  f32x4 acc[NA][NBF] = {};
  auto do_mfma = [&](bf16x8 (&fa)[NA], bf16x8 (&fb)[NBF]){
    __builtin_amdgcn_s_setprio(1);
    #pragma unroll
    for (int i=0;i<NA;i++)
      #pragma unroll
      for (int j=0;j<NBF;j++)
        acc[i][j] = mfma16(fa[i], fb[j], acc[i][j]);
    __builtin_amdgcn_s_setprio(0);
  };

  // prologue: stage tiles 0..2, wait tile 0, read frags(0)
  stage_tile(0); stage_tile(1); stage_tile(2);
  if constexpr (MODE==0) WAITVM(8); else WAITVM(4);
  barx();
  bf16x8 fEa[NA], fEb[NBF], fOa[NA], fOb[NBF];
  read_frags(0, fEa, fEb);

  for (int t=0; t<NKT; t+=2){
    // ---- even iter: cur=E, next->O ----
    if (t+3 < NKT)      { stage_tile(t+3); if constexpr (MODE==0) WAITVM(8); else WAITVM(4); }
    else if (t+3 == NKT){ if constexpr (MODE==0) WAITVM(4); else WAITVM(2); }
    else                { WAITVM(0); }
    barx();
    read_frags(t+1, fOa, fOb);
    do_mfma(fEa, fEb);
    // ---- odd iter: cur=O, next->E ----
    const int t2 = t+1;
    if (t2 < NKT-1){
      if (t2+3 < NKT)      { stage_tile(t2+3); if constexpr (MODE==0) WAITVM(8); else WAITVM(4); }
      else if (t2+3 == NKT){ if constexpr (MODE==0) WAITVM(4); else WAITVM(2); }
      else                 { WAITVM(0); }
      barx();
      read_frags(t2+1, fEa, fEb);
    }
    do_mfma(fOa, fOb);
  }

  // ---- epilogue ----
  #pragma unroll
  for (int i=0;i<NA;i++){
    const int m0 = row0 + wr*(BM/2) + i*16 + g4*4;
    #pragma unroll
    for (int j=0;j<NBF;j++){
      const int c = col0 + wc*(BN/4) + j*16 + lrow;
      #pragma unroll
      for (int r=0;r<4;r++){
        float v = acc[i][j][r];
        if (MODE==1){
          Outf[(size_t)(m0+r)*HID + c] = v;
        } else {
          if (wsel<2) v = v>0.f ? v+1.f : __expf(v);   // elu(v)+1
          bf16 bv = (bf16)v;
          if      (wsel==0) Qo[(size_t)(m0+r)*HID + c] = bv;
          else if (wsel==1) Kn[(size_t)(m0+r)*HID + c] = bv;
          else              Vn[(size_t)(m0+r)*HID + c] = bv;
        }
      }
    }
  }
}

// ---------------- transpose (M,HID)->(BH,D,L), coalesced both sides ----------------
__global__ __launch_bounds__(256) void trans_k(const bf16* __restrict__ Kn, const bf16* __restrict__ Vn,
                                               bf16* __restrict__ Kt, bf16* __restrict__ Vt){
  __shared__ bf16 T[64][72];
  const bf16* src = blockIdx.z ? Vn : Kn;
  bf16* dst = blockIdx.z ? Vt : Kt;
  const int bh = blockIdx.y;
  const int b = bh >> 4, h = bh & 15;
  const int l0 = blockIdx.x * 64;
  const int t = threadIdx.x;
  const int lr = t >> 2, c4 = t & 3;
  const bf16* s = src + ((size_t)(b*LL + l0 + lr))*HID + h*HD;
  *(bf16x8*)&T[lr][c4*8]      = *(const bf16x8*)&s[c4*8];
  *(bf16x8*)&T[lr][c4*8 + 32] = *(const bf16x8*)&s[c4*8 + 32];
  __syncthreads();
  bf16* dd = dst + ((size_t)bh*HD + lr)*LL + l0;
  bf16x8 o0, o1;
  #pragma unroll
  for (int e=0;e<8;e++){ o0[e] = T[c4*8+e][lr]; o1[e] = T[c4*8+32+e][lr]; }
  *(bf16x8*)&dd[c4*8] = o0;
  *(bf16x8*)&dd[c4*8+32] = o1;
}

// ---------------- pass1: per-chunk SkvT[e][d] = sum_j v_j[e] k_j[d], ksum[d] ----------------
__global__ __launch_bounds__(64) void pass1_k(const bf16* __restrict__ Kt, const bf16* __restrict__ Vt,
                                              float* __restrict__ SkvT, float* __restrict__ ksum)
{
  const int blk = blockIdx.x;                 // bh*NT + t
  const int bh = blk >> 5, t = blk & (NT-1);
  const int lane = threadIdx.x;
  const int lrow = lane&15, g4 = lane>>4, lk8 = g4*8;
  const bf16* vtb = Vt + (size_t)bh*HD*LL + t*CHUNK;
  const bf16* ktb = Kt + (size_t)bh*HD*LL + t*CHUNK;
  bf16x8 av[4][2], bk[4][2];
  #pragma unroll
  for (int i=0;i<4;i++)
    #pragma unroll
    for (int kk=0;kk<2;kk++){
      av[i][kk] = *(const bf16x8*)&vtb[(size_t)(i*16+lrow)*LL + kk*32 + lk8];
      bk[i][kk] = *(const bf16x8*)&ktb[(size_t)(i*16+lrow)*LL + kk*32 + lk8];
    }
  f32x4 acc[4][4] = {};
  #pragma unroll
  for (int i=0;i<4;i++)
    #pragma unroll
    for (int j=0;j<4;j++)
      #pragma unroll
      for (int kk=0;kk<2;kk++)
        acc[i][j] = mfma16(av[i][kk], bk[j][kk], acc[i][j]);
  float* so = SkvT + (size_t)blk*4096;
  #pragma unroll
  for (int i=0;i<4;i++)
    #pragma unroll
    for (int j=0;j<4;j++)
      #pragma unroll
      for (int r=0;r<4;r++)
        so[(i*16+g4*4+r)*64 + j*16+lrow] = acc[i][j][r];
  const bf16* krow = ktb + (size_t)lane*LL;
  float s = 0.f;
  #pragma unroll
  for (int c8=0;c8<8;c8++){
    bf16x8 v = *(const bf16x8*)&krow[c8*8];
    #pragma unroll
    for (int j=0;j<8;j++) s += (float)v[j];
  }
  ksum[(size_t)blk*64 + lane] = s;
}

// ---------------- pass2: exclusive prefix scan over chunks ----------------
__global__ __launch_bounds__(256) void pass2_k(const float* __restrict__ SkvT, const float* __restrict__ ksum,
                                               bf16* __restrict__ Sexcl, float* __restrict__ ksx)
{
  int gid = blockIdx.x*256 + threadIdx.x;
  if (gid < BHn*4096){
    int bh = gid >> 12, e = gid & 4095;
    float run = 0.f;
    size_t base = (size_t)bh*NT*4096 + e;
    for (int t=0;t<NT;t++){
      Sexcl[base + (size_t)t*4096] = (bf16)run;
      run += SkvT[base + (size_t)t*4096];
    }
  } else if (gid < BHn*4096 + BHn*64){
    int g2 = gid - BHn*4096;
    int bh = g2 >> 6, d = g2 & 63;
    float run = 0.f;
    size_t base = (size_t)bh*NT*64 + d;
    for (int t=0;t<NT;t++){
      ksx[base + (size_t)t*64] = run;
      run += ksum[base + (size_t)t*64];
    }
  }
}

// ---------------- pass3: per (b,h,chunk) output ----------------
__global__ __launch_bounds__(64) void pass3_k(const bf16* __restrict__ Q, const bf16* __restrict__ Kn,
                                              const bf16* __restrict__ Sexcl, const bf16* __restrict__ Vt,
                                              const float* __restrict__ ksx, bf16* __restrict__ Obuf)
{
  __shared__ bf16 P[64*72];
  const int blk = blockIdx.x;
  const int bh = blk>>5, t = blk&(NT-1);
  const int b = bh>>4, h = bh&15;
  const int lane = threadIdx.x;
  const int lrow = lane&15, g4 = lane>>4, lk8 = g4*8;
  const bf16* qb = Q  + ((size_t)(b*LL + t*CHUNK))*HID + h*HD;
  const bf16* kb = Kn + ((size_t)(b*LL + t*CHUNK))*HID + h*HD;
  bf16x8 aq[4][2], bk[4][2];
  #pragma unroll
  for (int i=0;i<4;i++)
    #pragma unroll
    for (int kk=0;kk<2;kk++){
      aq[i][kk] = *(const bf16x8*)&qb[(size_t)(i*16+lrow)*HID + kk*32 + lk8];
      bk[i][kk] = *(const bf16x8*)&kb[(size_t)(i*16+lrow)*HID + kk*32 + lk8];
    }
  f32x4 sacc[4][4] = {};
  #pragma unroll
  for (int i=0;i<4;i++)
    #pragma unroll
    for (int j=0;j<4;j++)
      #pragma unroll
      for (int kk=0;kk<2;kk++)
        sacc[i][j] = mfma16(aq[i][kk], bk[j][kk], sacc[i][j]);
  float rs[4][4];
  #pragma unroll
  for (int i=0;i<4;i++)
    #pragma unroll
    for (int r=0;r<4;r++){
      int irow = i*16 + g4*4 + r;
      float p = 0.f;
      #pragma unroll
      for (int j=0;j<4;j++){
        int jcol = j*16 + lrow;
        float v = (jcol <= irow) ? sacc[i][j][r] : 0.f;
        sacc[i][j][r] = v;
        p += v;
      }
      p += __shfl_xor(p,1); p += __shfl_xor(p,2);
      p += __shfl_xor(p,4); p += __shfl_xor(p,8);
      rs[i][r] = p;
    }
  #pragma unroll
  for (int i=0;i<4;i++)
    #pragma unroll
    for (int j=0;j<4;j++)
      #pragma unroll
      for (int r=0;r<4;r++)
        P[(i*16+g4*4+r)*72 + j*16+lrow] = (bf16)sacc[i][j][r];
  const float* kp = ksx + (size_t)blk*64;
  float zA[4];
  #pragma unroll
  for (int i=0;i<4;i++){
    float s = 0.f;
    #pragma unroll
    for (int kk=0;kk<2;kk++){
      const float* k8 = kp + kk*32 + lk8;
      bf16x8 q = aq[i][kk];
      #pragma unroll
      for (int j=0;j<8;j++) s += (float)q[j] * k8[j];
    }
    s += __shfl_xor(s,16); s += __shfl_xor(s,32);
    zA[i] = s;
  }
  const bf16* sb = Sexcl + (size_t)blk*4096;
  f32x4 oacc[4][4] = {};
  bf16x8 bs[4][2];
  #pragma unroll
  for (int j=0;j<4;j++)
    #pragma unroll
    for (int kk=0;kk<2;kk++)
      bs[j][kk] = *(const bf16x8*)&sb[(size_t)(j*16+lrow)*64 + kk*32 + lk8];
  #pragma unroll
  for (int i=0;i<4;i++)
    #pragma unroll
    for (int j=0;j<4;j++)
      #pragma unroll
      for (int kk=0;kk<2;kk++)
        oacc[i][j] = mfma16(aq[i][kk], bs[j][kk], oacc[i][j]);
  __syncthreads();
  const bf16* vb = Vt + (size_t)bh*HD*LL + t*CHUNK;
  bf16x8 bv[4][2], ap[4][2];
  #pragma unroll
  for (int j=0;j<4;j++)
    #pragma unroll
    for (int kk=0;kk<2;kk++)
      bv[j][kk] = *(const bf16x8*)&vb[(size_t)(j*16+lrow)*LL + kk*32 + lk8];
  #pragma unroll
  for (int i=0;i<4;i++)
    #pragma unroll
    for (int kk=0;kk<2;kk++)
      ap[i][kk] = *(const bf16x8*)&P[(i*16+lrow)*72 + kk*32 + lk8];
  #pragma unroll
  for (int i=0;i<4;i++)
    #pragma unroll
    for (int j=0;j<4;j++)
      #pragma unroll
      for (int kk=0;kk<2;kk++)
        oacc[i][j] = mfma16(ap[i][kk], bv[j][kk], oacc[i][j]);
  bf16* ob = Obuf + ((size_t)(b*LL + t*CHUNK))*HID + h*HD;
  #pragma unroll
  for (int i=0;i<4;i++)
    #pragma unroll
    for (int r=0;r<4;r++){
      float z = __shfl(zA[i], g4*4 + r) + rs[i][r];
      z = fmaxf(z, 1e-6f);
      float inv = 1.0f/z;
      int irow = i*16 + g4*4 + r;
      #pragma unroll
      for (int j=0;j<4;j++)
        ob[(size_t)irow*HID + j*16+lrow] = (bf16)(oacc[i][j][r]*inv);
    }
}

// ---------------- launch ----------------
extern "C" void kernel_launch(void* const* d_in, const int* in_sizes, int n_in,
                              void* d_out, int out_size, void* d_ws, size_t ws_size,
                              hipStream_t stream)
{
  const float* x  = (const float*)d_in[0];
  const float* Wq = (const float*)d_in[1];
  const float* Wk = (const float*)d_in[2];
  const float* Wv = (const float*)d_in[3];
  const float* Wo = (const float*)d_in[4];
  float* out = (float*)d_out;

  char* p = (char*)d_ws;
  auto alloc = [&](size_t bytes){ void* r = (void*)p; p += (bytes + 255) & ~(size_t)255; return r; };
  bf16* xb   = (bf16*)alloc((size_t)MM*HID*2);
  bf16* Wqb  = (bf16*)alloc((size_t)HID*HID*2);
  bf16* Wkb  = (bf16*)alloc((size_t)HID*HID*2);
  bf16* Wvb  = (bf16*)alloc((size_t)HID*HID*2);
  bf16* Wob  = (bf16*)alloc((size_t)HID*HID*2);
  bf16* Qb   = (bf16*)alloc((size_t)MM*HID*2);
  bf16* Knb  = (bf16*)alloc((size_t)MM*HID*2);
  bf16* Vnb  = (bf16*)alloc((size_t)MM*HID*2);
  bf16* Ktb  = (bf16*)alloc((size_t)MM*HID*2);        // (BH, D, L)
  bf16* Vtb  = (bf16*)alloc((size_t)MM*HID*2);        // (BH, D, L)
  bf16* Ob   = (bf16*)alloc((size_t)MM*HID*2);
  float* SkvT  = (float*)alloc((size_t)BHn*NT*4096*4);
  bf16*  Sexcl = (bf16*) alloc((size_t)BHn*NT*4096*2);
  float* ksum  = (float*)alloc((size_t)BHn*NT*64*4);
  float* ksx   = (float*)alloc((size_t)BHn*NT*64*4);

  cast_all_k<<<dim3(8192), 256, 0, stream>>>(x, Wq,Wk,Wv,Wo, xb, Wqb,Wkb,Wvb,Wob);
  gemm8_k<0><<<dim3(12,16), 512, 0, stream>>>(xb, Wqb,Wkb,Wvb, Qb,Knb,Vnb, nullptr);
  trans_k<<<dim3(LL/64, BHn, 2), 256, 0, stream>>>(Knb, Vnb, Ktb, Vtb);
  pass1_k<<<dim3(BHn*NT), 64, 0, stream>>>(Ktb, Vtb, SkvT, ksum);
  pass2_k<<<dim3((BHn*4096 + BHn*64 + 255)/256), 256, 0, stream>>>(SkvT, ksum, Sexcl, ksx);
  pass3_k<<<dim3(BHn*NT), 64, 0, stream>>>(Qb, Knb, Sexcl, Vtb, ksx, Ob);
  gemm8_k<1><<<dim3(8,32), 512, 0, stream>>>(Ob, Wob,nullptr,nullptr, nullptr,nullptr,nullptr, out);
}